// Round 4
// baseline (902.135 us; speedup 1.0000x reference)
//
#include <hip/hip_runtime.h>
#include <hip/hip_bf16.h>
#include <math.h>

// GraphConvLSTM: B=512, IN=256, H=128, T=100, N=22.
// Round 4: 512 threads/block (8 waves) -- grid is fixed at 512 blocks (one per
// batch, 2 blocks/CU), so occupancy must come from bigger blocks: 4 waves/SIMD
// instead of 2. Each wave owns one 16-col MFMA tile; gates split 4-way.
// Numerics unchanged: fp16 W single + h hi/lo split, fp32 gates.

#define B_   512
#define IN_  256
#define H_   128
#define T_   100
#define N_   22
#define NH   (N_ * H_)      // 2816
#define TNH  (T_ * NH)      // 281600
#define HP   136            // padded h row length in fp16 elems
#define THREADS 512

typedef __attribute__((ext_vector_type(8))) _Float16 half8_t;  // fp16x8 MFMA frag
typedef __attribute__((ext_vector_type(4))) float f32x4;       // MFMA accumulator

__device__ __forceinline__ float sigm(float x) {
    float e = __builtin_exp2f(x * -1.442695041f);            // e^{-x}
    return __builtin_amdgcn_rcpf(1.0f + e);
}
__device__ __forceinline__ float tanh_f(float x) {
    float a = fabsf(x);
    float e = __builtin_exp2f(a * -2.885390082f);            // e^{-2a}
    float r = (1.0f - e) * __builtin_amdgcn_rcpf(1.0f + e);
    return copysignf(r, x);
}

__global__ void __launch_bounds__(THREADS, 4)
gclstm_kernel(const float* __restrict__ x,
              const float* __restrict__ wi_w, const float* __restrict__ wi_b,
              const float* __restrict__ wf_w, const float* __restrict__ wf_b,
              const float* __restrict__ wo_w, const float* __restrict__ wo_b,
              const float* __restrict__ wc_w, const float* __restrict__ wc_b,
              const float* __restrict__ gcn_w, const float* __restrict__ gcn_b,
              float* __restrict__ out)
{
    __shared__ __align__(16) _Float16 h_hi[32][HP];      // 8704 B (rows 22..31 zero)
    __shared__ __align__(16) _Float16 h_lo[32][HP];      // 8704 B
    __shared__ __align__(16) float hw_lds[N_][H_ + 1];   // 11352 B
    __shared__ float xp_lds[4][H_];
    __shared__ __align__(16) float xrow[IN_];

    const int t    = threadIdx.x;      // 0..511
    const int b    = blockIdx.x;
    const int ho   = t & (H_ - 1);     // thread-layout channel
    const int mg   = t >> 7;           // node group 0..3 (wave-uniform)
    const int wid  = t >> 6;           // wave id 0..7 (owns cols 16*wid..+15)
    const int lane = t & 63;
    const int lrow = lane & 15;        // row (A) / col (B,C) within 16x16 tile
    const int lkg  = lane >> 4;        // k-group 0..3

    // ---- stage x row; zero h ----
    if (t < IN_ / 4) {
        reinterpret_cast<float4*>(xrow)[t] =
            reinterpret_cast<const float4*>(x + (size_t)b * IN_)[t];
    }
    for (int e = t; e < 32 * HP / 2; e += THREADS) ((int*)h_hi)[e] = 0;
    for (int e = t; e < 32 * HP / 2; e += THREADS) ((int*)h_lo)[e] = 0;
    __syncthreads();

    // ---- x projections: thread computes gate `mg` at channel `ho` ----
    {
        const float* wg = (mg == 0) ? wi_w : (mg == 1) ? wf_w : (mg == 2) ? wo_w : wc_w;
        const float* bg = (mg == 0) ? wi_b : (mg == 1) ? wf_b : (mg == 2) ? wo_b : wc_b;
        const float* rg = wg + (size_t)ho * IN_;
        float acc = bg[ho];
        #pragma unroll
        for (int k4 = 0; k4 < IN_ / 4; ++k4) {
            float4 xv = reinterpret_cast<const float4*>(xrow)[k4];
            float4 wv = reinterpret_cast<const float4*>(rg)[k4];
            acc += wv.x * xv.x + wv.y * xv.y + wv.z * xv.z + wv.w * xv.w;
        }
        xp_lds[mg][ho] = acc;
    }

    // ---- gcn_w B-fragments, single fp16, persistent (16 VGPRs/thread) ----
    // B-frag (16x16x32): lane holds W[k = 32*ks + 8*lkg + i][col = 16*wid + lrow]
    half8_t Wf[4];
    #pragma unroll
    for (int ks = 0; ks < 4; ++ks) {
        #pragma unroll
        for (int i = 0; i < 8; ++i) {
            const int k   = 32 * ks + 8 * lkg + i;
            const int col = 16 * wid + lrow;
            Wf[ks][i] = (_Float16)gcn_w[k * H_ + col];
        }
    }
    __syncthreads();

    const float gb   = gcn_b[ho];
    const float xi_r = xp_lds[0][ho] + gb;
    const float xf_r = xp_lds[1][ho] + gb;
    const float xo_r = xp_lds[2][ho] + gb;
    const float xc_r = xp_lds[3][ho] + gb;

    float c_reg[6];
    #pragma unroll
    for (int i = 0; i < 6; ++i) c_reg[i] = 0.0f;

    float* outb = out + (size_t)b * TNH + ho;

    // D^{-1/2}: deg 13 for nodes 0,9; 5 for 3,6,12,15; 4 otherwise
    #define D13 0.2773500981126146f
    #define D5  0.4472135954999579f
    #define D4  0.5f
    const float DINV[22] = {D13, D4, D4, D5, D4, D4, D5, D4, D4, D13, D4,
                            D4,  D5, D4, D4, D5, D4, D4, D4, D4, D4,  D4};

    for (int step = 0; step < T_; ++step) {
        // ================= phase 1: HW = (hh+hl) @ W via MFMA =================
        f32x4 acc0 = (f32x4)(0.0f);   // rows 0..15
        f32x4 acc1 = (f32x4)(0.0f);   // rows 16..31 (22..31 are zero)

        #pragma unroll
        for (int ks = 0; ks < 4; ++ks) {
            const int ko = 32 * ks + 8 * lkg;
            const half8_t Ah0 = *reinterpret_cast<const half8_t*>(&h_hi[lrow][ko]);
            const half8_t Ah1 = *reinterpret_cast<const half8_t*>(&h_hi[16 + lrow][ko]);
            const half8_t Al0 = *reinterpret_cast<const half8_t*>(&h_lo[lrow][ko]);
            const half8_t Al1 = *reinterpret_cast<const half8_t*>(&h_lo[16 + lrow][ko]);
            acc0 = __builtin_amdgcn_mfma_f32_16x16x32_f16(Ah0, Wf[ks], acc0, 0, 0, 0);
            acc0 = __builtin_amdgcn_mfma_f32_16x16x32_f16(Al0, Wf[ks], acc0, 0, 0, 0);
            acc1 = __builtin_amdgcn_mfma_f32_16x16x32_f16(Ah1, Wf[ks], acc1, 0, 0, 0);
            acc1 = __builtin_amdgcn_mfma_f32_16x16x32_f16(Al1, Wf[ks], acc1, 0, 0, 0);
        }
        // C layout: col = 16*wid + lrow, row = 4*lkg + i (+16 for acc1)
        #pragma unroll
        for (int i = 0; i < 4; ++i) {
            const int row = 4 * lkg + i;
            hw_lds[row][16 * wid + lrow] = acc0[i];
            const int row2 = 16 + row;
            if (row2 < N_) hw_lds[row2][16 * wid + lrow] = acc1[i];
        }
        __syncthreads();

        // ================= phase 2: A-mix + gates (thread layout) =================
        float tt[22];
        #pragma unroll
        for (int m = 0; m < 22; ++m) tt[m] = DINV[m] * hw_lds[m][ho];

        const float S0 = tt[0] + tt[2] + tt[5] + tt[8] + tt[11];
        const float S1 = tt[0] + tt[1] + tt[4] + tt[7] + tt[10];
        const float S2 = tt[0] + tt[3] + tt[6] + tt[9] + tt[12] + tt[15];
        const float S3 = tt[9] + tt[14] + tt[17] + tt[19] + tt[21];
        const float S4 = tt[9] + tt[13] + tt[16] + tt[18] + tt[20];

        float* outs = outb + (size_t)step * NH;

        #define UPD(n, nn, SSexpr, KK) {                                        \
            const float g  = DINV[n] * ((SSexpr) - (KK) * tt[n]);               \
            const float it = sigm(xi_r + g);                                    \
            const float ft = sigm(xf_r + g);                                    \
            const float ot = sigm(xo_r + g);                                    \
            const float ct = tanh_f(xc_r + g);                                  \
            const float cn = ft * c_reg[nn] + it * ct;                          \
            c_reg[nn] = cn;                                                     \
            const float hn = ot * tanh_f(cn);                                   \
            outs[(n) * H_] = hn;                                                \
            const _Float16 hh = (_Float16)hn;                                   \
            h_hi[n][ho] = hh;                                                   \
            h_lo[n][ho] = (_Float16)(hn - (float)hh);                           \
        }

        if (mg == 0) {          // nodes 0..5
            UPD(0, 0, S0 + S1 + S2, 3.0f)
            UPD(1, 1, S1, 1.0f)
            UPD(2, 2, S0, 1.0f)
            UPD(3, 3, S2, 1.0f)
            UPD(4, 4, S1, 1.0f)
            UPD(5, 5, S0, 1.0f)
        } else if (mg == 1) {   // nodes 6..10
            UPD(6, 0, S2, 1.0f)
            UPD(7, 1, S1, 1.0f)
            UPD(8, 2, S0, 1.0f)
            UPD(9, 3, S2 + S3 + S4, 3.0f)
            UPD(10, 4, S1, 1.0f)
        } else if (mg == 2) {   // nodes 11..16
            UPD(11, 0, S0, 1.0f)
            UPD(12, 1, S2, 1.0f)
            UPD(13, 2, S4, 1.0f)
            UPD(14, 3, S3, 1.0f)
            UPD(15, 4, S2, 1.0f)
            UPD(16, 5, S4, 1.0f)
        } else {                // nodes 17..21
            UPD(17, 0, S3, 1.0f)
            UPD(18, 1, S4, 1.0f)
            UPD(19, 2, S3, 1.0f)
            UPD(20, 3, S4, 1.0f)
            UPD(21, 4, S3, 1.0f)
        }
        #undef UPD
        __syncthreads();
    }
}

extern "C" void kernel_launch(void* const* d_in, const int* in_sizes, int n_in,
                              void* d_out, int out_size, void* d_ws, size_t ws_size,
                              hipStream_t stream) {
    const float* x     = (const float*)d_in[0];
    const float* wi_w  = (const float*)d_in[1];
    const float* wi_b  = (const float*)d_in[2];
    const float* wf_w  = (const float*)d_in[3];
    const float* wf_b  = (const float*)d_in[4];
    const float* wo_w  = (const float*)d_in[5];
    const float* wo_b  = (const float*)d_in[6];
    const float* wc_w  = (const float*)d_in[7];
    const float* wc_b  = (const float*)d_in[8];
    const float* gcn_w = (const float*)d_in[9];
    const float* gcn_b = (const float*)d_in[10];
    float* out = (float*)d_out;

    gclstm_kernel<<<dim3(B_), dim3(THREADS), 0, stream>>>(
        x, wi_w, wi_b, wf_w, wf_b, wo_w, wo_b, wc_w, wc_b, gcn_w, gcn_b, out);
}

// Round 5
// 794.480 us; speedup vs baseline: 1.1355x; 1.1355x over previous
//
#include <hip/hip_runtime.h>
#include <hip/hip_bf16.h>
#include <math.h>

// GraphConvLSTM: B=512, IN=256, H=128, T=100, N=22.
// Round 5: (1) 32x32x16 MFMA, phase-1 on waves 0-3 only (halve A-read LDS
// traffic); (2) transposed XOR-swizzled hw_T[ho][32] -> b128 LDS writes/reads,
// conflict-free; (3) shared-exp gate math: 7 trans/element instead of 10.
// Numerics: fp16 W single + h hi/lo split, fp32 gates (unchanged class).

#define B_   512
#define IN_  256
#define H_   128
#define T_   100
#define N_   22
#define NH   (N_ * H_)      // 2816
#define TNH  (T_ * NH)      // 281600
#define HP   136            // padded h row length in fp16 elems (272B rows)
#define THREADS 512
#define LOG2E 1.442695041f

typedef __attribute__((ext_vector_type(8)))  _Float16 half8_t;  // fp16x8 MFMA frag
typedef __attribute__((ext_vector_type(16))) float    f32x16;   // 32x32 accumulator

__global__ void __launch_bounds__(THREADS, 4)
gclstm_kernel(const float* __restrict__ x,
              const float* __restrict__ wi_w, const float* __restrict__ wi_b,
              const float* __restrict__ wf_w, const float* __restrict__ wf_b,
              const float* __restrict__ wo_w, const float* __restrict__ wo_b,
              const float* __restrict__ wc_w, const float* __restrict__ wc_b,
              const float* __restrict__ gcn_w, const float* __restrict__ gcn_b,
              float* __restrict__ out)
{
    __shared__ __align__(16) _Float16 h_hi[32][HP];   // 8704 B (rows 22..31 zero)
    __shared__ __align__(16) _Float16 h_lo[32][HP];   // 8704 B
    __shared__ __align__(16) float    hw_T[H_ * 32];  // 16384 B, [ho][m] 16B-unit swizzled
    __shared__ float xp_lds[4][H_];
    __shared__ __align__(16) float xrow[IN_];

    const int t     = threadIdx.x;      // 0..511
    const int b     = blockIdx.x;
    const int ho    = t & (H_ - 1);     // thread-layout channel
    const int mg    = t >> 7;           // gate/node group 0..3 (wave-uniform)
    const int wid   = t >> 6;           // wave id 0..7
    const int lane  = t & 63;
    const int l31   = lane & 31;        // row (A) / col (B,C) within 32x32 tile
    const int khalf = lane >> 5;        // k-half 0..1 (8 elems each of K=16)

    // ---- stage x row; zero h ----
    if (t < IN_ / 4) {
        reinterpret_cast<float4*>(xrow)[t] =
            reinterpret_cast<const float4*>(x + (size_t)b * IN_)[t];
    }
    for (int e = t; e < 32 * HP / 2; e += THREADS) ((int*)h_hi)[e] = 0;
    for (int e = t; e < 32 * HP / 2; e += THREADS) ((int*)h_lo)[e] = 0;
    __syncthreads();

    // ---- x projections: thread computes gate `mg` at channel `ho` ----
    {
        const float* wg = (mg == 0) ? wi_w : (mg == 1) ? wf_w : (mg == 2) ? wo_w : wc_w;
        const float* bg = (mg == 0) ? wi_b : (mg == 1) ? wf_b : (mg == 2) ? wo_b : wc_b;
        const float* rg = wg + (size_t)ho * IN_;
        float acc = bg[ho];
        #pragma unroll
        for (int k4 = 0; k4 < IN_ / 4; ++k4) {
            float4 xv = reinterpret_cast<const float4*>(xrow)[k4];
            float4 wv = reinterpret_cast<const float4*>(rg)[k4];
            acc += wv.x * xv.x + wv.y * xv.y + wv.z * xv.z + wv.w * xv.w;
        }
        xp_lds[mg][ho] = acc;
    }

    // ---- gcn_w B-fragments (waves 0..3 only), fp16, persistent (32 VGPRs) ----
    // B-frag (32x32x16): lane holds W[k = 16*kk + 8*khalf + i][col = 32*wid + l31]
    half8_t Bf[8];
    if (wid < 4) {
        const int col = 32 * wid + l31;
        #pragma unroll
        for (int kk = 0; kk < 8; ++kk) {
            #pragma unroll
            for (int i = 0; i < 8; ++i) {
                Bf[kk][i] = (_Float16)gcn_w[(16 * kk + 8 * khalf + i) * H_ + col];
            }
        }
    }
    __syncthreads();

    // ---- per-thread step-invariant gate constants ----
    const float gb   = gcn_b[ho];
    const float xi_r = xp_lds[0][ho] + gb;
    const float xf_r = xp_lds[1][ho] + gb;
    const float xo_r = xp_lds[2][ho] + gb;
    const float xc_r = xp_lds[3][ho] + gb;
    const float Ei   = __builtin_exp2f(-LOG2E * xi_r);          // e^{-xi}
    const float Ef   = __builtin_exp2f(-LOG2E * xf_r);
    const float Eo   = __builtin_exp2f(-LOG2E * xo_r);
    const float E2c  = __builtin_exp2f(-2.0f * LOG2E * xc_r);   // e^{-2xc}

    float c_reg[6];
    #pragma unroll
    for (int i = 0; i < 6; ++i) c_reg[i] = 0.0f;

    float* outb = out + (size_t)b * TNH + ho;

    // D^{-1/2}: deg 13 for nodes 0,9; 5 for 3,6,12,15; 4 otherwise
    #define D13 0.2773500981126146f
    #define D5  0.4472135954999579f
    #define D4  0.5f
    const float DINV[22] = {D13, D4, D4, D5, D4, D4, D5, D4, D4, D13, D4,
                            D4,  D5, D4, D4, D5, D4, D4, D4, D4, D4,  D4};

    for (int step = 0; step < T_; ++step) {
        // ============ phase 1: HW = (hh+hl) @ W via 32x32x16 MFMA (waves 0-3) ============
        if (wid < 4) {
            f32x16 acc = (f32x16)(0.0f);
            #pragma unroll
            for (int kk = 0; kk < 8; ++kk) {
                const int ko = 16 * kk + 8 * khalf;
                const half8_t Ah = *reinterpret_cast<const half8_t*>(&h_hi[l31][ko]);
                const half8_t Al = *reinterpret_cast<const half8_t*>(&h_lo[l31][ko]);
                acc = __builtin_amdgcn_mfma_f32_32x32x16_f16(Ah, Bf[kk], acc, 0, 0, 0);
                acc = __builtin_amdgcn_mfma_f32_32x32x16_f16(Al, Bf[kk], acc, 0, 0, 0);
            }
            // C layout: col = l31 (+32*wid), row = (reg&3) + 8*(reg>>2) + 4*khalf
            // regs 4q..4q+3 -> rows 8q+4khalf..+3 (contiguous) -> one b128 write
            const int col = 32 * wid + l31;
            #pragma unroll
            for (int q = 0; q < 4; ++q) {
                float4 v = make_float4(acc[4 * q], acc[4 * q + 1],
                                       acc[4 * q + 2], acc[4 * q + 3]);
                const int unit = (2 * q + khalf) ^ (col & 7);   // 16B-unit swizzle
                *reinterpret_cast<float4*>(&hw_T[col * 32 + unit * 4]) = v;
            }
        }
        __syncthreads();

        // ============ phase 2: A-mix + gates (all 8 waves, thread layout) ============
        float tt[24];
        #pragma unroll
        for (int u = 0; u < 6; ++u) {
            const int unit = u ^ (ho & 7);
            float4 v = *reinterpret_cast<const float4*>(&hw_T[ho * 32 + unit * 4]);
            tt[4 * u + 0] = v.x; tt[4 * u + 1] = v.y;
            tt[4 * u + 2] = v.z; tt[4 * u + 3] = v.w;
        }
        #pragma unroll
        for (int m = 0; m < 22; ++m) tt[m] *= DINV[m];

        const float S0 = tt[0] + tt[2] + tt[5] + tt[8] + tt[11];
        const float S1 = tt[0] + tt[1] + tt[4] + tt[7] + tt[10];
        const float S2 = tt[0] + tt[3] + tt[6] + tt[9] + tt[12] + tt[15];
        const float S3 = tt[9] + tt[14] + tt[17] + tt[19] + tt[21];
        const float S4 = tt[9] + tt[13] + tt[16] + tt[18] + tt[20];

        float* outs = outb + (size_t)step * NH;

        // shared-exp gates: i/f/o = 1/(1+E*Eg), tanh = (1-e2)/(1+e2), E = e^{-g}
        #define UPD(n, nn, SSexpr, KK) {                                        \
            const float g   = DINV[n] * ((SSexpr) - (KK) * tt[n]);              \
            const float E   = __builtin_exp2f(-LOG2E * g);                      \
            const float it  = __builtin_amdgcn_rcpf(1.0f + E * Ei);             \
            const float ft  = __builtin_amdgcn_rcpf(1.0f + E * Ef);             \
            const float ot  = __builtin_amdgcn_rcpf(1.0f + E * Eo);             \
            const float e2  = fminf(E * E * E2c, 1e30f);                        \
            const float ct  = (1.0f - e2) * __builtin_amdgcn_rcpf(1.0f + e2);   \
            const float cn  = ft * c_reg[nn] + it * ct;                         \
            c_reg[nn] = cn;                                                     \
            const float e2n = fminf(__builtin_exp2f(-2.0f * LOG2E * cn), 1e30f);\
            const float th  = (1.0f - e2n) * __builtin_amdgcn_rcpf(1.0f + e2n); \
            const float hn  = ot * th;                                          \
            outs[(n) * H_] = hn;                                                \
            const _Float16 hh = (_Float16)hn;                                   \
            h_hi[n][ho] = hh;                                                   \
            h_lo[n][ho] = (_Float16)(hn - (float)hh);                           \
        }

        if (mg == 0) {          // nodes 0..5
            UPD(0, 0, S0 + S1 + S2, 3.0f)
            UPD(1, 1, S1, 1.0f)
            UPD(2, 2, S0, 1.0f)
            UPD(3, 3, S2, 1.0f)
            UPD(4, 4, S1, 1.0f)
            UPD(5, 5, S0, 1.0f)
        } else if (mg == 1) {   // nodes 6..10
            UPD(6, 0, S2, 1.0f)
            UPD(7, 1, S1, 1.0f)
            UPD(8, 2, S0, 1.0f)
            UPD(9, 3, S2 + S3 + S4, 3.0f)
            UPD(10, 4, S1, 1.0f)
        } else if (mg == 2) {   // nodes 11..16
            UPD(11, 0, S0, 1.0f)
            UPD(12, 1, S2, 1.0f)
            UPD(13, 2, S4, 1.0f)
            UPD(14, 3, S3, 1.0f)
            UPD(15, 4, S2, 1.0f)
            UPD(16, 5, S4, 1.0f)
        } else {                // nodes 17..21
            UPD(17, 0, S3, 1.0f)
            UPD(18, 1, S4, 1.0f)
            UPD(19, 2, S3, 1.0f)
            UPD(20, 3, S4, 1.0f)
            UPD(21, 4, S3, 1.0f)
        }
        #undef UPD
        __syncthreads();
    }
}

extern "C" void kernel_launch(void* const* d_in, const int* in_sizes, int n_in,
                              void* d_out, int out_size, void* d_ws, size_t ws_size,
                              hipStream_t stream) {
    const float* x     = (const float*)d_in[0];
    const float* wi_w  = (const float*)d_in[1];
    const float* wi_b  = (const float*)d_in[2];
    const float* wf_w  = (const float*)d_in[3];
    const float* wf_b  = (const float*)d_in[4];
    const float* wo_w  = (const float*)d_in[5];
    const float* wo_b  = (const float*)d_in[6];
    const float* wc_w  = (const float*)d_in[7];
    const float* wc_b  = (const float*)d_in[8];
    const float* gcn_w = (const float*)d_in[9];
    const float* gcn_b = (const float*)d_in[10];
    float* out = (float*)d_out;

    gclstm_kernel<<<dim3(B_), dim3(THREADS), 0, stream>>>(
        x, wi_w, wi_b, wf_w, wf_b, wo_w, wo_b, wc_w, wc_b, gcn_w, gcn_b, out);
}